// Round 17
// baseline (61.778 us; speedup 1.0000x reference)
//
#include <hip/hip_runtime.h>

// Problem constants (match reference)
#define BB   8
#define CC   1024
#define TT   4096
#define HH   16
#define KK   31

#define NT    256               // threads per block (4 independent waves)
#define RPT   16                // outputs per thread
#define NRD   12                // ds_read_b128 per thread window (48 floats)
#define WCH   264               // 16B chunks per wave buffer: 4 + 256 + 4
#define SEGW  1024              // outputs per wave-segment (quarter row)

typedef float floatx4 __attribute__((ext_vector_type(4)));
typedef const float __attribute__((address_space(1)))* gptr_t;   // global
typedef float __attribute__((address_space(3)))* lptr_t;         // LDS

// Involution swizzle p = q ^ ((q>>3)&7): bijective and closed on [0,264)
// (q>=256 fixed). Wave-logical chunk q holds x[s0 - 16 + 4q .. +3] (sources
// clamped at true row edges; garbage zero-patched in registers).
// Read pattern q = 4*l + c (enumerated l=0..15): quads hit exactly 2x per
// 16-lane phase = the free wave64 floor. DMA dest is lane-contiguous.
__device__ __forceinline__ int swz(int q) { return q ^ ((q >> 3) & 7); }

// --- softmax over the 31 taps of each of the 16 heads -> d_ws ---
__global__ void lwconv_softmax_w(const float* __restrict__ w, float* __restrict__ wsm) {
    int h = threadIdx.x;
    if (h < HH) {
        float buf[KK];
        float m = -1e30f;
        #pragma unroll
        for (int k = 0; k < KK; ++k) { buf[k] = w[h * KK + k]; m = fmaxf(m, buf[k]); }
        float s = 0.f;
        #pragma unroll
        for (int k = 0; k < KK; ++k) { buf[k] = expf(buf[k] - m); s += buf[k]; }
        float inv = 1.f / s;
        #pragma unroll
        for (int k = 0; k < KK; ++k) wsm[h * KK + k] = buf[k] * inv;
    }
}

// --- main: block = (batch, 8-channel group); 4 waves each own a quarter-row
//     with a PRIVATE double buffer; 8 channel iterations, depth-2 DMA
//     prefetch, counted vmcnt, zero barriers. ---
// out[t] = bias + sum_k w[k] * x[t + k - 15]
__global__ __launch_bounds__(NT) void lwconv_main(const float* __restrict__ inp,
                                                  const float* __restrict__ wsm,
                                                  const float* __restrict__ bias,
                                                  float* __restrict__ out) {
    __shared__ floatx4 buf[4][2][WCH];       // 33,792 B -> 4 blocks/CU exactly

    const int blk  = blockIdx.x;             // b*128 + g
    const int b    = blk >> 7;
    const int c0   = (blk & 127) << 3;       // 8 consecutive channels, same head
    const int head = c0 >> 6;
    const int tid  = threadIdx.x;
    const int wv   = tid >> 6;               // wave 0..3
    const int l    = tid & 63;               // lane

    const int s0 = wv * SEGW;                // this wave's first output t

    const float* base  = inp + ((size_t)b * CC + c0) * TT;
    float*       obase = out + ((size_t)b * CC + c0) * TT;

    // stage channel i's quarter-row into buf[wv][i&1]: exactly 5 exec-uniform
    // DMA covering chunks [0,256) + [200,264) (overlap = same bytes, benign)
    auto stage = [&](int i) {
        const float* rp = base + (size_t)i * TT;
        floatx4* wbuf = &buf[wv][i & 1][0];
        #pragma unroll
        for (int j = 0; j < 5; ++j) {
            const int p = (j == 4) ? (200 + l) : (64 * j + l);   // physical chunk
            int f = s0 - 16 + 4 * swz(p);                        // source float
            f = min(max(f, 0), TT - 4);                          // clamp row edges
            __builtin_amdgcn_global_load_lds((gptr_t)(rp + f),
                                             (lptr_t)(&wbuf[p]), 16, 0, 0);
        }
    };

    stage(0);
    stage(1);

    // uniform pre-softmaxed weights + bias (scalar loads, overlap DMA)
    const float* wh = wsm + head * KK;
    float w[KK];
    #pragma unroll
    for (int k = 0; k < KK; ++k) w[k] = wh[k];
    const float bval = bias[head];

    #pragma unroll 1
    for (int r = 0; r < BB; ++r) {
        // Counted wait for row r's 5 DMA (per-wave in-order retirement).
        // Issue order/iter: [5 DMA][4 stores]. Steady queue at wait:
        // DMA_r(5), st_{r-2}(4), DMA_{r+1}(5), st_{r-1}(4) -> keep 13.
        if (r == 0)
            asm volatile("s_waitcnt vmcnt(5)" ::: "memory");
        else if (r == 1)
            asm volatile("s_waitcnt vmcnt(9)" ::: "memory");
        else if (r == BB - 1)
            asm volatile("s_waitcnt vmcnt(8)" ::: "memory");
        else
            asm volatile("s_waitcnt vmcnt(13)" ::: "memory");

        // window: 12 ds_read_b128; compiler inserts fine-grained lgkm waits
        // so FMA below interleaves with the reads (no explicit drain here)
        float xv[4 * NRD];
        #pragma unroll
        for (int c = 0; c < NRD; ++c) {
            floatx4 v = buf[wv][r & 1][swz(4 * l + c)];
            #pragma unroll
            for (int e = 0; e < 4; ++e) xv[4 * c + e] = v[e];
        }

        // register patch of row-edge padding (garbage from clamped DMA):
        // xv[e] = x[s0 + 16l - 16 + e]; tid 0 -> e<16 all pad; tid 255 ->
        // e>=32 all pad (4064+e >= 4096). Whole-16 zeroing, no per-e tests.
        if (tid == 0) {
            #pragma unroll
            for (int e = 0; e < 16; ++e) xv[e] = 0.f;
        }
        if (tid == NT - 1) {
            #pragma unroll
            for (int e = 32; e < 48; ++e) xv[e] = 0.f;
        }

        // compute channel r's 16 outputs
        float acc[RPT];
        #pragma unroll
        for (int p = 0; p < RPT; ++p) acc[p] = bval;
        #pragma unroll
        for (int k = 0; k < KK; ++k) {
            #pragma unroll
            for (int p = 0; p < RPT; ++p)
                acc[p] = fmaf(xv[p + 1 + k], w[k], acc[p]);
        }

        // drain my LDS reads (free: FMA consumed them), THEN refill my buffer
        asm volatile("s_waitcnt lgkmcnt(0)" ::: "memory");
        __builtin_amdgcn_sched_barrier(0);
        if (r + 2 < BB) stage(r + 2);
        __builtin_amdgcn_sched_barrier(0);   // keep DMA-before-stores issue order

        float* orow = obase + (size_t)r * TT + s0 + (l << 4);
        #pragma unroll
        for (int c2 = 0; c2 < RPT / 4; ++c2) {
            floatx4 o = { acc[4 * c2], acc[4 * c2 + 1],
                          acc[4 * c2 + 2], acc[4 * c2 + 3] };
            *reinterpret_cast<floatx4*>(orow + 4 * c2) = o;
        }
    }
}

extern "C" void kernel_launch(void* const* d_in, const int* in_sizes, int n_in,
                              void* d_out, int out_size, void* d_ws, size_t ws_size,
                              hipStream_t stream) {
    const float* inp    = (const float*)d_in[0];   // (B, C, T) fp32
    const float* weight = (const float*)d_in[1];   // (H, 1, K) fp32
    const float* bias   = (const float*)d_in[2];   // (H,) fp32
    float* out = (float*)d_out;
    float* wsm = (float*)d_ws;                     // H*K softmaxed weights

    lwconv_softmax_w<<<1, 64, 0, stream>>>(weight, wsm);

    const int blocks = BB * (CC / 8);              // 1024 = 4 blocks/CU exactly
    lwconv_main<<<blocks, NT, 0, stream>>>(inp, wsm, bias, out);
}